// Round 1
// baseline (570.813 us; speedup 1.0000x reference)
//
#include <hip/hip_runtime.h>

#define BB 1024
#define TT 512
#define KK 64

// ---- wave(64)-wide reductions via butterfly shuffles ----
__device__ __forceinline__ float wmaxf(float x) {
#pragma unroll
  for (int off = 32; off > 0; off >>= 1) x = fmaxf(x, __shfl_xor(x, off, 64));
  return x;
}
__device__ __forceinline__ float wsumf(float x) {
#pragma unroll
  for (int off = 32; off > 0; off >>= 1) x += __shfl_xor(x, off, 64);
  return x;
}
__device__ __forceinline__ int wsumi(int x) {
#pragma unroll
  for (int off = 32; off > 0; off >>= 1) x += __shfl_xor(x, off, 64);
  return x;
}

// One block = one batch element. 128 threads = 2 waves:
//   wave0: forward algorithm (logZ) + gold score -> nll = logZ - gold
//   wave1: viterbi recurrence (bp in LDS) + backtrace -> path
// The two waves touch disjoint LDS buffers and never synchronize.
extern "C" __global__ void __launch_bounds__(128) crf_all_kernel(
    const float* __restrict__ em,      // [B,T,K]
    const int* __restrict__ tags,      // [B,T]
    const int* __restrict__ mask,      // [B,T]
    const float* __restrict__ trans,   // [K,K]
    const float* __restrict__ startt,  // [K]
    const float* __restrict__ endt,    // [K]
    float* __restrict__ out) {         // [B] nll ++ [B,T] path (as float)
  __shared__ unsigned char bp[(TT - 1) * KK];     // 32704 B backpointers
  __shared__ __align__(16) float pbuf[KK];        // forward exp(alpha-M)
  __shared__ __align__(16) float vbuf[KK];        // viterbi v broadcast

  const int b = blockIdx.x;
  const int lane = threadIdx.x & 63;
  const float* emb = em + (size_t)b * TT * KK;
  const int* maskb = mask + b * TT;
  const int* tagsb = tags + b * TT;

  if (threadIdx.x < 64) {
    // ---------------- wave0: forward (logZ) + gold score ----------------
    // lane j holds column j of E = exp(trans): E[i][j] over i, in registers.
    float Ecol[KK];
#pragma unroll
    for (int i = 0; i < KK; ++i) Ecol[i] = __expf(trans[i * KK + lane]);

    float alpha = startt[lane] + emb[lane];
    for (int t = 1; t < TT; ++t) {
      float emv = emb[t * KK + lane];   // coalesced, issued early
      int m = maskb[t];
      float M = wmaxf(alpha);
      pbuf[lane] = __expf(alpha - M);
      __builtin_amdgcn_wave_barrier();  // same-wave LDS ops are in-order; fence compiler
      float s0 = 0.f, s1 = 0.f, s2 = 0.f, s3 = 0.f;
#pragma unroll
      for (int i = 0; i < KK; i += 4) {
        float4 pv = *(const float4*)&pbuf[i];   // same-address broadcast ds_read_b128
        s0 = fmaf(pv.x, Ecol[i + 0], s0);
        s1 = fmaf(pv.y, Ecol[i + 1], s1);
        s2 = fmaf(pv.z, Ecol[i + 2], s2);
        s3 = fmaf(pv.w, Ecol[i + 3], s3);
      }
      __builtin_amdgcn_wave_barrier();
      float na = __logf((s0 + s1) + (s2 + s3)) + M + emv;
      alpha = (m != 0) ? na : alpha;
    }
    // logZ = logsumexp(alpha + end)
    float x = alpha + endt[lane];
    float M2 = wmaxf(x);
    float S = wsumf(__expf(x - M2));
    float logZ = __logf(S) + M2;

    // gold score: lane j covers t = u*64 + j
    float acc = 0.f;
    int msum = 0;
#pragma unroll
    for (int u = 0; u < TT / KK; ++u) {
      int t = u * KK + lane;
      int tg = tagsb[t];
      int m = maskb[t];
      msum += m;
      float mf = (float)m;
      acc = fmaf(emb[t * KK + tg], mf, acc);
      if (t >= 1) acc = fmaf(trans[tagsb[t - 1] * KK + tg], mf, acc);
    }
    acc = wsumf(acc);
    msum = wsumi(msum);
    if (lane == 0) {
      float gold = acc + startt[tagsb[0]] + endt[tagsb[msum - 1]];
      out[b] = logZ - gold;
    }
  } else {
    // ---------------- wave1: viterbi + backtrace ----------------
    // lane j holds column j of trans in registers.
    float Tcol[KK];
#pragma unroll
    for (int i = 0; i < KK; ++i) Tcol[i] = trans[i * KK + lane];

    float v = startt[lane] + emb[lane];
    for (int t = 1; t < TT; ++t) {
      float emv = emb[t * KK + lane];
      int m = maskb[t];
      vbuf[lane] = v;
      __builtin_amdgcn_wave_barrier();
      float best = -3.402823466e38f;
      int bi = 0;
      // ascending i + strict '>' == np.argmax first-index tie-break.
      // scores are plain fp32 adds -> bitwise-matches reference recurrence.
#pragma unroll
      for (int i = 0; i < KK; i += 4) {
        float4 vv = *(const float4*)&vbuf[i];   // broadcast
        float c0 = vv.x + Tcol[i + 0];
        float c1 = vv.y + Tcol[i + 1];
        float c2 = vv.z + Tcol[i + 2];
        float c3 = vv.w + Tcol[i + 3];
        if (c0 > best) { best = c0; bi = i + 0; }
        if (c1 > best) { best = c1; bi = i + 1; }
        if (c2 > best) { best = c2; bi = i + 2; }
        if (c3 > best) { best = c3; bi = i + 3; }
      }
      __builtin_amdgcn_wave_barrier();
      bp[(t - 1) * KK + lane] = (unsigned char)((m != 0) ? bi : lane);
      v = (m != 0) ? (best + emv) : v;
    }
    // last = argmax(v + end), first-index on exact ties
    float sc = v + endt[lane];
    int idx = lane;
#pragma unroll
    for (int off = 32; off > 0; off >>= 1) {
      float osc = __shfl_xor(sc, off, 64);
      int oidx = __shfl_xor(idx, off, 64);
      if (osc > sc || (osc == sc && oidx < idx)) { sc = osc; idx = oidx; }
    }
    // backtrace: all lanes follow the same chain (uniform broadcast reads)
    int tag = idx;
    float* pout = out + BB + (size_t)b * TT;
    for (int t = TT - 1; t >= 1; --t) {
      if (lane == 0) pout[t] = (float)tag;
      tag = bp[(t - 1) * KK + tag];
    }
    if (lane == 0) pout[0] = (float)tag;
  }
}

extern "C" void kernel_launch(void* const* d_in, const int* in_sizes, int n_in,
                              void* d_out, int out_size, void* d_ws, size_t ws_size,
                              hipStream_t stream) {
  (void)in_sizes; (void)n_in; (void)out_size; (void)d_ws; (void)ws_size;
  const float* em = (const float*)d_in[0];
  const int* tags = (const int*)d_in[1];
  const int* mask = (const int*)d_in[2];
  const float* trans = (const float*)d_in[3];
  const float* startt = (const float*)d_in[4];
  const float* endt = (const float*)d_in[5];
  float* out = (float*)d_out;
  crf_all_kernel<<<dim3(BB), dim3(128), 0, stream>>>(em, tags, mask, trans,
                                                     startt, endt, out);
}